// Round 1
// baseline (998.553 us; speedup 1.0000x reference)
//
#include <hip/hip_runtime.h>
#include <math.h>

#define TWO_PI 6.28318530717958647692f

// ---------------------------------------------------------------------------
// Stage 1: per (image, v-chunk-of-32) block.
//   Phase A: P[n][v] = sum_m X[n][m] * cas(2pi v' m / 256)   (v' = 64+vchunk*32+v)
//            Q[n][v] = sum_m X[n][m] * cas(-2pi v' m / 256)
//   Phase B: Dc[u][v] = sum_n cos(2pi u' n/256) P[n][v] + sin(2pi u' n/256) Q[n][v]
//   (u' = 64+u).  Dc written into d_out (reused as scratch for stage 2).
// ---------------------------------------------------------------------------
__global__ __launch_bounds__(256) void dht_stage1(const float* __restrict__ x,
                                                  float* __restrict__ dc)
{
    __shared__ float c1[256], c2[256], cT[256], sT[256];
    __shared__ float Psh[256][32];
    __shared__ float Qsh[256][32];

    const int t   = threadIdx.x;
    const int img = blockIdx.x >> 2;
    const int vcb = blockIdx.x & 3;

    {
        float s, c;
        sincosf((float)t * (TWO_PI / 256.0f), &s, &c);
        c1[t] = c + s;   // cas(theta)
        c2[t] = c - s;   // cas(-theta)
        cT[t] = c;
        sT[t] = s;
    }
    __syncthreads();

    const float* __restrict__ X = x + (size_t)img * 65536;

    // ---- Phase A ----
    {
        const int v  = t & 31;
        const int ng = t >> 5;               // 0..7
        const int vp = 64 + vcb * 32 + v;    // v' in [64,192)

        for (int k = 0; k < 32; k += 8) {
            const int n0 = ng * 32 + k;
            float aP[8], aQ[8];
#pragma unroll
            for (int i = 0; i < 8; ++i) { aP[i] = 0.0f; aQ[i] = 0.0f; }
            int idx = 0;
            for (int m = 0; m < 256; m += 4) {
                float4 xr[8];
#pragma unroll
                for (int i = 0; i < 8; ++i)
                    xr[i] = *(const float4*)(X + (size_t)(n0 + i) * 256 + m);
                const float* xf = (const float*)xr;
#pragma unroll
                for (int j = 0; j < 4; ++j) {
                    const float w1 = c1[idx];
                    const float w2 = c2[idx];
                    idx = (idx + vp) & 255;
#pragma unroll
                    for (int i = 0; i < 8; ++i) {
                        const float xv = xf[i * 4 + j];
                        aP[i] = fmaf(xv, w1, aP[i]);
                        aQ[i] = fmaf(xv, w2, aQ[i]);
                    }
                }
            }
#pragma unroll
            for (int i = 0; i < 8; ++i) {
                Psh[n0 + i][v] = aP[i];
                Qsh[n0 + i][v] = aQ[i];
            }
        }
    }
    __syncthreads();

    // ---- Phase B ----
    {
        const int vq = t & 7;
        const int ug = t >> 3;    // 0..31
        const int v4 = vq * 4;
        const int u0 = ug * 4;

        float acc[4][4];
#pragma unroll
        for (int i = 0; i < 4; ++i)
#pragma unroll
            for (int j = 0; j < 4; ++j) acc[i][j] = 0.0f;

        int iu[4], du[4];
#pragma unroll
        for (int i = 0; i < 4; ++i) { iu[i] = 0; du[i] = (64 + u0 + i) & 255; }

        for (int n = 0; n < 256; ++n) {
            const float4 Pv = *(const float4*)&Psh[n][v4];
            const float4 Qv = *(const float4*)&Qsh[n][v4];
#pragma unroll
            for (int i = 0; i < 4; ++i) {
                const float cu = cT[iu[i]];
                const float su = sT[iu[i]];
                iu[i] = (iu[i] + du[i]) & 255;
                acc[i][0] = fmaf(cu, Pv.x, acc[i][0]); acc[i][0] = fmaf(su, Qv.x, acc[i][0]);
                acc[i][1] = fmaf(cu, Pv.y, acc[i][1]); acc[i][1] = fmaf(su, Qv.y, acc[i][1]);
                acc[i][2] = fmaf(cu, Pv.z, acc[i][2]); acc[i][2] = fmaf(su, Qv.z, acc[i][2]);
                acc[i][3] = fmaf(cu, Pv.w, acc[i][3]); acc[i][3] = fmaf(su, Qv.w, acc[i][3]);
            }
        }

        float* __restrict__ Gp = dc + (size_t)img * 16384;
#pragma unroll
        for (int i = 0; i < 4; ++i) {
            *(float4*)&Gp[(size_t)(u0 + i) * 128 + vcb * 32 + v4] =
                make_float4(acc[i][0], acc[i][1], acc[i][2], acc[i][3]);
        }
    }
}

// ---------------------------------------------------------------------------
// Stage 2: one block per image. Loads the 128x128 cropped DHT (Dc) from d_out
// into LDS, applies the full 128x128 DHT, and overwrites the same d_out region.
// ---------------------------------------------------------------------------
__global__ __launch_bounds__(256) void dht_stage2(float* __restrict__ g)
{
    __shared__ float D[128][128];        // 64 KB
    __shared__ float c1[128], c2[128], cT[128], sT[128];
    __shared__ float Psh[128][32];       // 16 KB
    __shared__ float Qsh[128][32];       // 16 KB

    const int t = threadIdx.x;
    float* __restrict__ G = g + (size_t)blockIdx.x * 16384;

    {
        const float4* src = (const float4*)G;
        float4* dst = (float4*)&D[0][0];
        for (int i = t; i < 4096; i += 256) dst[i] = src[i];
    }
    if (t < 128) {
        float s, c;
        sincosf((float)t * (TWO_PI / 128.0f), &s, &c);
        c1[t] = c + s;
        c2[t] = c - s;
        cT[t] = c;
        sT[t] = s;
    }
    __syncthreads();

    for (int vcb = 0; vcb < 4; ++vcb) {
        // ---- Phase A2 ----
        {
            const int v  = t & 31;
            const int pg = t >> 5;            // 0..7
            const int vv = vcb * 32 + v;      // 0..127

            for (int k = 0; k < 16; k += 8) {
                const int p0 = pg * 16 + k;
                float aP[8], aQ[8];
#pragma unroll
                for (int i = 0; i < 8; ++i) { aP[i] = 0.0f; aQ[i] = 0.0f; }
                int idx = 0;
                for (int m = 0; m < 128; m += 4) {
                    float4 xr[8];
#pragma unroll
                    for (int i = 0; i < 8; ++i)
                        xr[i] = *(const float4*)&D[p0 + i][m];
                    const float* xf = (const float*)xr;
#pragma unroll
                    for (int j = 0; j < 4; ++j) {
                        const float w1 = c1[idx];
                        const float w2 = c2[idx];
                        idx = (idx + vv) & 127;
#pragma unroll
                        for (int i = 0; i < 8; ++i) {
                            const float xv = xf[i * 4 + j];
                            aP[i] = fmaf(xv, w1, aP[i]);
                            aQ[i] = fmaf(xv, w2, aQ[i]);
                        }
                    }
                }
#pragma unroll
                for (int i = 0; i < 8; ++i) {
                    Psh[p0 + i][v] = aP[i];
                    Qsh[p0 + i][v] = aQ[i];
                }
            }
        }
        __syncthreads();

        // ---- Phase B2 ----
        {
            const int vq = t & 7;
            const int ug = t >> 3;   // 0..31
            const int v4 = vq * 4;
            const int u0 = ug * 4;

            float acc[4][4];
#pragma unroll
            for (int i = 0; i < 4; ++i)
#pragma unroll
                for (int j = 0; j < 4; ++j) acc[i][j] = 0.0f;

            int iu[4], du[4];
#pragma unroll
            for (int i = 0; i < 4; ++i) { iu[i] = 0; du[i] = (u0 + i) & 127; }

            for (int p = 0; p < 128; ++p) {
                const float4 Pv = *(const float4*)&Psh[p][v4];
                const float4 Qv = *(const float4*)&Qsh[p][v4];
#pragma unroll
                for (int i = 0; i < 4; ++i) {
                    const float cu = cT[iu[i]];
                    const float su = sT[iu[i]];
                    iu[i] = (iu[i] + du[i]) & 127;
                    acc[i][0] = fmaf(cu, Pv.x, acc[i][0]); acc[i][0] = fmaf(su, Qv.x, acc[i][0]);
                    acc[i][1] = fmaf(cu, Pv.y, acc[i][1]); acc[i][1] = fmaf(su, Qv.y, acc[i][1]);
                    acc[i][2] = fmaf(cu, Pv.z, acc[i][2]); acc[i][2] = fmaf(su, Qv.z, acc[i][2]);
                    acc[i][3] = fmaf(cu, Pv.w, acc[i][3]); acc[i][3] = fmaf(su, Qv.w, acc[i][3]);
                }
            }

            // Barrier: all P/Q reads done before next chunk overwrites them.
            __syncthreads();

#pragma unroll
            for (int i = 0; i < 4; ++i) {
                *(float4*)&G[(size_t)(u0 + i) * 128 + vcb * 32 + v4] =
                    make_float4(acc[i][0], acc[i][1], acc[i][2], acc[i][3]);
            }
        }
    }
}

extern "C" void kernel_launch(void* const* d_in, const int* in_sizes, int n_in,
                              void* d_out, int out_size, void* d_ws, size_t ws_size,
                              hipStream_t stream)
{
    const float* x = (const float*)d_in[0];
    float* out = (float*)d_out;

    // Stage 1: 512 images * 4 v-chunks. Writes cropped DHT (Dc) into d_out.
    dht_stage1<<<dim3(2048), dim3(256), 0, stream>>>(x, out);
    // Stage 2: one block per image; reads Dc from d_out, overwrites with result.
    dht_stage2<<<dim3(512), dim3(256), 0, stream>>>(out);
}

// Round 2
// 276.766 us; speedup vs baseline: 3.6079x; 3.6079x over previous
//
#include <hip/hip_runtime.h>
#include <math.h>

// ---------------------------------------------------------------------------
// out = DHT2_128( crop_center_128( DHT2_256(x) ) ), x: (512, 256, 256) fp32.
// All four GEMM passes run on bf16 MFMA (16x16x32). Twiddle tables are
// generated once per launch into d_ws as bf16 and read from global (L2-hot).
// Intermediates (P/Q) transpose through XOR-swizzled LDS.
//
// ws layout (bf16 elements):
//   W1t [256][256] at 0      : row j<128 -> cas(2pi (64+j) m /256) (P cols)
//                              row j>=128 -> cas(2pi (320-j) m /256) (Q cols)
//   W2  [128][512] at 65536  : [u][k] k<256 -> cos(2pi (64+u) k /256)
//                                      k>=256 -> sin(2pi (64+u)(k-256)/256)
//   W3t [256][128] at 131072 : 128-point analog of W1t (mult j / 256-j)
//   W4  [128][256] at 163840 : 128-point analog of W2
// ---------------------------------------------------------------------------

typedef __attribute__((ext_vector_type(8))) short bfrag;   // 8 bf16 (4 VGPRs)
typedef __attribute__((ext_vector_type(4))) float ffrag;   // 4 fp32 acc

#define PI2_256 0.0245436926061702597f
#define PI2_128 0.0490873852123405194f

__device__ __forceinline__ unsigned short f2bf(float f) {
    union { float f; unsigned int u; } v; v.f = f;
    unsigned int r = v.u + 0x7fffu + ((v.u >> 16) & 1u);
    return (unsigned short)(r >> 16);
}

__device__ __forceinline__ bfrag pack8(float4 a, float4 b) {
    bfrag r;
    r[0] = (short)f2bf(a.x); r[1] = (short)f2bf(a.y);
    r[2] = (short)f2bf(a.z); r[3] = (short)f2bf(a.w);
    r[4] = (short)f2bf(b.x); r[5] = (short)f2bf(b.y);
    r[6] = (short)f2bf(b.z); r[7] = (short)f2bf(b.w);
    return r;
}

// ---------------------------------------------------------------------------
__global__ __launch_bounds__(256) void gen_tables(unsigned short* __restrict__ ws)
{
    const int id = blockIdx.x * 256 + threadIdx.x;   // 65536 threads
    // W1t: 65536 elems
    {
        const int j = id >> 8, m = id & 255;
        const int mult = (j < 128) ? (64 + j) : (320 - j);
        const int idx = (mult * m) & 255;
        float s, c; sincosf((float)idx * PI2_256, &s, &c);
        ws[id] = f2bf(c + s);
    }
    // W2: 65536 elems
    {
        const int u = id >> 9, k = id & 511;
        const int up = 64 + u;
        float s, c, val;
        if (k < 256) { sincosf((float)((up * k) & 255) * PI2_256, &s, &c); val = c; }
        else         { sincosf((float)((up * (k - 256)) & 255) * PI2_256, &s, &c); val = s; }
        ws[65536 + id] = f2bf(val);
    }
    if (id < 32768) {
        // W3t
        {
            const int j = id >> 7, m = id & 127;
            const int mult = (j < 128) ? j : (256 - j);
            const int idx = (mult * m) & 127;
            float s, c; sincosf((float)idx * PI2_128, &s, &c);
            ws[131072 + id] = f2bf(c + s);
        }
        // W4
        {
            const int u = id >> 8, k = id & 255;
            float s, c, val;
            if (k < 128) { sincosf((float)((u * k) & 127) * PI2_128, &s, &c); val = c; }
            else         { sincosf((float)((u * (k - 128)) & 127) * PI2_128, &s, &c); val = s; }
            ws[163840 + id] = f2bf(val);
        }
    }
}

// ---------------------------------------------------------------------------
// Stage 1: one block per image, 512 threads (8 waves).
//   Phase A: C[n][c] = sum_m X[n][m] * W1t[c][m]   (256x256x256)
//            -> PQt LDS (swizzled): c<128: PQt[c][n], c>=128: PQt[c-128][256+n]
//   Phase B: Dc[u][v] = sum_k W2[u][k] * PQt[v][k] (128x128x512) -> d_out fp32
// ---------------------------------------------------------------------------
__global__ __launch_bounds__(512, 2) void stage1(const float* __restrict__ X,
                                                 const unsigned short* __restrict__ ws,
                                                 float* __restrict__ dc)
{
    __shared__ unsigned short PQt[128 * 512];   // 128 KiB, XOR-swizzled (granule = 8 bf16)

    const int t  = threadIdx.x;
    const int w  = t >> 6;          // wave 0..7
    const int ln = t & 15;          // lane & 15
    const int q  = (t & 63) >> 4;   // quad 0..3
    const int img = blockIdx.x;

    const float* __restrict__ Xi = X + (size_t)img * 65536;
    const unsigned short* __restrict__ W1 = ws;            // [256][256]
    const unsigned short* __restrict__ W2 = ws + 65536;    // [128][512]

    // ---- Phase A ----
    {
        ffrag acc[2][16];
#pragma unroll
        for (int mt = 0; mt < 2; ++mt)
#pragma unroll
            for (int nt = 0; nt < 16; ++nt)
                acc[mt][nt] = (ffrag){0.f, 0.f, 0.f, 0.f};

        const int rowA0 = 32 * w;
        for (int kk = 0; kk < 8; ++kk) {
            const int k = kk * 32 + q * 8;
            bfrag A[2];
#pragma unroll
            for (int mt = 0; mt < 2; ++mt) {
                const float* xp = Xi + (size_t)(rowA0 + 16 * mt + ln) * 256 + k;
                const float4 x0 = *(const float4*)xp;
                const float4 x1 = *(const float4*)(xp + 4);
                A[mt] = pack8(x0, x1);
            }
#pragma unroll
            for (int nt = 0; nt < 16; ++nt) {
                const int j = nt * 16 + ln;
                const bfrag B = *(const bfrag*)(W1 + j * 256 + k);
#pragma unroll
                for (int mt = 0; mt < 2; ++mt)
                    acc[mt][nt] = __builtin_amdgcn_mfma_f32_16x16x32_bf16(A[mt], B, acc[mt][nt], 0, 0, 0);
            }
        }
        // Store to swizzled PQt: lane's 4 regs are 4 consecutive n (k2 dim).
#pragma unroll
        for (int mt = 0; mt < 2; ++mt) {
#pragma unroll
            for (int nt = 0; nt < 16; ++nt) {
                const int c  = nt * 16 + ln;
                const int v  = c & 127;
                const int kb = ((c < 128) ? 0 : 256) + rowA0 + 16 * mt + 4 * q;
                const unsigned int lo = (unsigned int)f2bf(acc[mt][nt][0]) |
                                        ((unsigned int)f2bf(acc[mt][nt][1]) << 16);
                const unsigned int hi = (unsigned int)f2bf(acc[mt][nt][2]) |
                                        ((unsigned int)f2bf(acc[mt][nt][3]) << 16);
                const int phys = v * 512 + ((((kb >> 3) ^ (v & 7)) << 3)) + (kb & 7);
                *(uint2*)&PQt[phys] = make_uint2(lo, hi);
            }
        }
    }
    __syncthreads();

    // ---- Phase B ----
    {
        ffrag acc[8];
#pragma unroll
        for (int nt = 0; nt < 8; ++nt) acc[nt] = (ffrag){0.f, 0.f, 0.f, 0.f};

        const int u0 = 16 * w;
        for (int kk = 0; kk < 16; ++kk) {
            const int k = kk * 32 + q * 8;
            const bfrag A = *(const bfrag*)(W2 + (size_t)(u0 + ln) * 512 + k);
#pragma unroll
            for (int nt = 0; nt < 8; ++nt) {
                const int v = nt * 16 + ln;
                const int g = (k >> 3) ^ (v & 7);
                const bfrag B = *(const bfrag*)&PQt[v * 512 + (g << 3)];
                acc[nt] = __builtin_amdgcn_mfma_f32_16x16x32_bf16(A, B, acc[nt], 0, 0, 0);
            }
        }
        float* __restrict__ D = dc + (size_t)img * 16384;
#pragma unroll
        for (int nt = 0; nt < 8; ++nt) {
#pragma unroll
            for (int r = 0; r < 4; ++r) {
                const int u = u0 + 4 * q + r;
                const int v = nt * 16 + ln;
                D[u * 128 + v] = acc[nt][r];
            }
        }
    }
}

// ---------------------------------------------------------------------------
// Stage 2: one block per image, 256 threads (4 waves). Dc buffered in LDS
// (bf16, swizzled) BEFORE any output store -> no cross-image race.
//   Phase A2: C3[p][c] = sum_m Dcb[p][m] * W3t[jsel(c)][m]  (128x128x128)
//   Phase B2: Out[u][64*vh+v] = sum_k W4[u][k] * PQ2[v][k]  (128x64x256)
// ---------------------------------------------------------------------------
__global__ __launch_bounds__(256, 2) void stage2(const unsigned short* __restrict__ ws,
                                                 float* __restrict__ io)
{
    __shared__ unsigned short Dcb[128 * 128];   // 32 KiB swizzled [p][m]
    __shared__ unsigned short PQ2[64 * 256];    // 32 KiB swizzled [v][k]

    const int t  = threadIdx.x;
    const int w  = t >> 6;          // wave 0..3
    const int ln = t & 15;
    const int q  = (t & 63) >> 4;
    const int img = blockIdx.x;

    float* __restrict__ G = io + (size_t)img * 16384;
    const unsigned short* __restrict__ W3 = ws + 131072;   // [256][128]
    const unsigned short* __restrict__ W4 = ws + 163840;   // [128][256]

    // Load Dc fp32 -> Dcb bf16 (swizzled).
    {
        const int p = t >> 1, half = t & 1;
        const float* src = G + p * 128 + half * 64;
#pragma unroll
        for (int g = 0; g < 8; ++g) {
            const float4 a = *(const float4*)(src + g * 8);
            const float4 b = *(const float4*)(src + g * 8 + 4);
            const int m0 = half * 64 + g * 8;
            const int gran = (m0 >> 3) ^ (p & 7);
            uint4 val;
            val.x = (unsigned int)f2bf(a.x) | ((unsigned int)f2bf(a.y) << 16);
            val.y = (unsigned int)f2bf(a.z) | ((unsigned int)f2bf(a.w) << 16);
            val.z = (unsigned int)f2bf(b.x) | ((unsigned int)f2bf(b.y) << 16);
            val.w = (unsigned int)f2bf(b.z) | ((unsigned int)f2bf(b.w) << 16);
            *(uint4*)&Dcb[p * 128 + gran * 8] = val;
        }
    }
    __syncthreads();

    for (int vh = 0; vh < 2; ++vh) {
        // ---- Phase A2 ----
        ffrag acc[2][8];
#pragma unroll
        for (int mt = 0; mt < 2; ++mt)
#pragma unroll
            for (int nt = 0; nt < 8; ++nt)
                acc[mt][nt] = (ffrag){0.f, 0.f, 0.f, 0.f};

        const int p0 = 32 * w;
        for (int kk = 0; kk < 4; ++kk) {
            const int k = kk * 32 + q * 8;
            bfrag A[2];
#pragma unroll
            for (int mt = 0; mt < 2; ++mt) {
                const int p = p0 + 16 * mt + ln;
                const int g = (k >> 3) ^ (p & 7);
                A[mt] = *(const bfrag*)&Dcb[p * 128 + g * 8];
            }
#pragma unroll
            for (int nt = 0; nt < 8; ++nt) {
                const int c = nt * 16 + ln;
                const int j = (c < 64) ? (64 * vh + c) : (128 + 64 * vh + (c - 64));
                const bfrag B = *(const bfrag*)(W3 + j * 128 + k);
#pragma unroll
                for (int mt = 0; mt < 2; ++mt)
                    acc[mt][nt] = __builtin_amdgcn_mfma_f32_16x16x32_bf16(A[mt], B, acc[mt][nt], 0, 0, 0);
            }
        }
        __syncthreads();   // vh=1: previous B2 must finish reading PQ2
#pragma unroll
        for (int mt = 0; mt < 2; ++mt) {
#pragma unroll
            for (int nt = 0; nt < 8; ++nt) {
                const int c  = nt * 16 + ln;
                const int v  = c & 63;
                const int kb = ((c < 64) ? 0 : 128) + p0 + 16 * mt + 4 * q;
                const unsigned int lo = (unsigned int)f2bf(acc[mt][nt][0]) |
                                        ((unsigned int)f2bf(acc[mt][nt][1]) << 16);
                const unsigned int hi = (unsigned int)f2bf(acc[mt][nt][2]) |
                                        ((unsigned int)f2bf(acc[mt][nt][3]) << 16);
                const int phys = v * 256 + ((((kb >> 3) ^ (v & 7)) << 3)) + (kb & 7);
                *(uint2*)&PQ2[phys] = make_uint2(lo, hi);
            }
        }
        __syncthreads();

        // ---- Phase B2 ----
        ffrag o[2][4];
#pragma unroll
        for (int mt = 0; mt < 2; ++mt)
#pragma unroll
            for (int nt = 0; nt < 4; ++nt)
                o[mt][nt] = (ffrag){0.f, 0.f, 0.f, 0.f};

        const int u0 = 32 * w;
        for (int kk = 0; kk < 8; ++kk) {
            const int k = kk * 32 + q * 8;
            bfrag A[2];
#pragma unroll
            for (int mt = 0; mt < 2; ++mt)
                A[mt] = *(const bfrag*)(W4 + (size_t)(u0 + 16 * mt + ln) * 256 + k);
#pragma unroll
            for (int nt = 0; nt < 4; ++nt) {
                const int v = nt * 16 + ln;
                const int g = (k >> 3) ^ (v & 7);
                const bfrag B = *(const bfrag*)&PQ2[v * 256 + (g << 3)];
#pragma unroll
                for (int mt = 0; mt < 2; ++mt)
                    o[mt][nt] = __builtin_amdgcn_mfma_f32_16x16x32_bf16(A[mt], B, o[mt][nt], 0, 0, 0);
            }
        }
#pragma unroll
        for (int mt = 0; mt < 2; ++mt) {
#pragma unroll
            for (int nt = 0; nt < 4; ++nt) {
#pragma unroll
                for (int r = 0; r < 4; ++r) {
                    const int u = u0 + 16 * mt + 4 * q + r;
                    const int v = 64 * vh + nt * 16 + ln;
                    G[u * 128 + v] = o[mt][nt][r];
                }
            }
        }
    }
}

// ---------------------------------------------------------------------------
extern "C" void kernel_launch(void* const* d_in, const int* in_sizes, int n_in,
                              void* d_out, int out_size, void* d_ws, size_t ws_size,
                              hipStream_t stream)
{
    const float* x = (const float*)d_in[0];
    float* out = (float*)d_out;
    unsigned short* tw = (unsigned short*)d_ws;   // needs 393,216 bytes

    gen_tables<<<dim3(256), dim3(256), 0, stream>>>(tw);
    stage1<<<dim3(512), dim3(512), 0, stream>>>(x, tw, out);
    stage2<<<dim3(512), dim3(256), 0, stream>>>(tw, out);
}